// Round 1
// baseline (157.008 us; speedup 1.0000x reference)
//
#include <hip/hip_runtime.h>
#include <math.h>

typedef unsigned int u32;

#define NBINS 10
#define NE 9            // interior edges
#define TPB 256

// z-space bin edges: ZE[j] = logit((j+1)/9.9999), f32.
// For t in {0,1}: g = |sigmoid(x)-t| = sigmoid((1-2t)*x) = sigmoid(z),
// so (g >= (j+1)/9.9999) <=> (z >= ZE[j]).  bce = softplus(z).
__device__ __forceinline__ void ghm_accum4(float4 xv, float4 tv,
                                           float* __restrict__ s, int* __restrict__ c) {
    const float ZE[NE] = {
        -2.1972135f, -1.3862819f, -0.84728357f, -0.40544844f,
         2.0000200e-5f, 0.40549011f, 0.84733119f, 1.3863444f, 2.1973246f
    };
    float xs[4] = {xv.x, xv.y, xv.z, xv.w};
    float ts[4] = {tv.x, tv.y, tv.z, tv.w};
    #pragma unroll
    for (int k = 0; k < 4; ++k) {
        float xx = xs[k], tt = ts[k];
        float z   = xx * fmaf(tt, -2.0f, 1.0f);          // (1-2t)*x
        float e   = __expf(-fabsf(z));                   // exp(-|z|)
        float bce = fmaxf(z, 0.0f) + __logf(1.0f + e);   // softplus(z) = stable BCE
        s[0] += bce;                                     // cumulative bin>=0 sum
        #pragma unroll
        for (int j = 0; j < NE; ++j) {
            bool m = (z >= ZE[j]);
            c[j]   += m ? 1 : 0;                         // cumulative count, bin >= j+1
            s[j+1] += m ? bce : 0.0f;                    // cumulative bce sum, bin >= j+1
        }
    }
}

// Full-wave (64-lane) DPP sum; valid result in lane 63. Zero DS ops.
// Canonical GFX9 sequence: row_shr 1,2,4,8 then row_bcast:15 (rows 1,3),
// row_bcast:31 (rows 2,3), each as u = update_dpp(0, v, ...); v += u
// so masked/out-of-row lanes add the identity.
__device__ __forceinline__ float wred_f32(float v) {
    int u;
    u = __builtin_amdgcn_update_dpp(0, __float_as_int(v), 0x111, 0xf, 0xf, false); v += __int_as_float(u);
    u = __builtin_amdgcn_update_dpp(0, __float_as_int(v), 0x112, 0xf, 0xf, false); v += __int_as_float(u);
    u = __builtin_amdgcn_update_dpp(0, __float_as_int(v), 0x114, 0xf, 0xf, false); v += __int_as_float(u);
    u = __builtin_amdgcn_update_dpp(0, __float_as_int(v), 0x118, 0xf, 0xf, false); v += __int_as_float(u);
    u = __builtin_amdgcn_update_dpp(0, __float_as_int(v), 0x142, 0xa, 0xf, false); v += __int_as_float(u);
    u = __builtin_amdgcn_update_dpp(0, __float_as_int(v), 0x143, 0xc, 0xf, false); v += __int_as_float(u);
    return v;
}
__device__ __forceinline__ int wred_i32(int v) {
    int u;
    u = __builtin_amdgcn_update_dpp(0, v, 0x111, 0xf, 0xf, false); v += u;
    u = __builtin_amdgcn_update_dpp(0, v, 0x112, 0xf, 0xf, false); v += u;
    u = __builtin_amdgcn_update_dpp(0, v, 0x114, 0xf, 0xf, false); v += u;
    u = __builtin_amdgcn_update_dpp(0, v, 0x118, 0xf, 0xf, false); v += u;
    u = __builtin_amdgcn_update_dpp(0, v, 0x142, 0xa, 0xf, false); v += u;
    u = __builtin_amdgcn_update_dpp(0, v, 0x143, 0xc, 0xf, false); v += u;
    return v;
}

// Hot loop is pure VALU + global loads: no LDS atomics, no rcp.
// launch_bounds(256,4): cap VGPR at 128 (expect ~50-64 actual -> still 8 waves/SIMD),
// avoids spill risk a forced 64-cap would carry.
__global__ __launch_bounds__(TPB, 4) void ghm_pass1(const float4* __restrict__ x,
                                                    const float4* __restrict__ t,
                                                    float* __restrict__ partS,
                                                    u32* __restrict__ partC, int n4) {
    float s[NBINS];
    int   c[NE];
    #pragma unroll
    for (int b = 0; b < NBINS; ++b) s[b] = 0.0f;
    #pragma unroll
    for (int j = 0; j < NE; ++j) c[j] = 0;

    const int T   = gridDim.x * blockDim.x;
    const int tid = blockIdx.x * blockDim.x + threadIdx.x;
    int i = tid;
    // unroll x2: 4 global loads in flight before compute
    for (; i + T < n4; i += 2 * T) {
        float4 xa = x[i];
        float4 xb = x[i + T];
        float4 ta = t[i];
        float4 tb = t[i + T];
        ghm_accum4(xa, ta, s, c);
        ghm_accum4(xb, tb, s, c);
    }
    for (; i < n4; i += T) ghm_accum4(x[i], t[i], s, c);

    // wave reduce (VALU-only DPP), then 4 waves -> block via tiny LDS handoff
    #pragma unroll
    for (int b = 0; b < NBINS; ++b) s[b] = wred_f32(s[b]);
    #pragma unroll
    for (int j = 0; j < NE; ++j) c[j] = wred_i32(c[j]);

    __shared__ float smS[4][NBINS];
    __shared__ int   smC[4][NE];
    const int lane = threadIdx.x & 63;
    const int wave = threadIdx.x >> 6;
    if (lane == 63) {
        #pragma unroll
        for (int b = 0; b < NBINS; ++b) smS[wave][b] = s[b];
        #pragma unroll
        for (int j = 0; j < NE; ++j) smC[wave][j] = c[j];
    }
    __syncthreads();
    if (threadIdx.x < NBINS) {
        partS[(size_t)blockIdx.x * NBINS + threadIdx.x] =
            smS[0][threadIdx.x] + smS[1][threadIdx.x] + smS[2][threadIdx.x] + smS[3][threadIdx.x];
    } else if (threadIdx.x >= 64 && threadIdx.x < 64 + NE) {
        int j = threadIdx.x - 64;
        partC[(size_t)blockIdx.x * NE + j] =
            (u32)(smC[0][j] + smC[1][j] + smC[2][j] + smC[3][j]);
    }
    // every parts slot written every launch: no ws zero-init needed
}

__global__ __launch_bounds__(256) void ghm_finalize(const float* __restrict__ partS,
                                                    const u32* __restrict__ partC,
                                                    float* __restrict__ out,
                                                    int nblocks, float n_total) {
    double aS[NBINS];
    double aC[NE];
    #pragma unroll
    for (int b = 0; b < NBINS; ++b) aS[b] = 0.0;
    #pragma unroll
    for (int j = 0; j < NE; ++j) aC[j] = 0.0;

    for (int blk = threadIdx.x; blk < nblocks; blk += 256) {
        #pragma unroll
        for (int b = 0; b < NBINS; ++b) aS[b] += (double)partS[blk * NBINS + b];
        #pragma unroll
        for (int j = 0; j < NE; ++j) aC[j] += (double)partC[blk * NE + j];
    }
    // one tiny block: shuffle butterfly is fine here
    #pragma unroll
    for (int off = 32; off; off >>= 1) {
        #pragma unroll
        for (int b = 0; b < NBINS; ++b) aS[b] += __shfl_down(aS[b], off, 64);
        #pragma unroll
        for (int j = 0; j < NE; ++j) aC[j] += __shfl_down(aC[j], off, 64);
    }

    __shared__ double smS[4][NBINS];
    __shared__ double smC[4][NE];
    const int lane = threadIdx.x & 63;
    const int wave = threadIdx.x >> 6;
    if (lane == 0) {
        #pragma unroll
        for (int b = 0; b < NBINS; ++b) smS[wave][b] = aS[b];
        #pragma unroll
        for (int j = 0; j < NE; ++j) smC[wave][j] = aC[j];
    }
    __syncthreads();

    if (threadIdx.x == 0) {
        double Scum[NBINS + 1], Ccum[NBINS + 1];
        Scum[NBINS] = 0.0;
        Ccum[NBINS] = 0.0;
        Ccum[0] = (double)n_total;                       // every element lands in some bin
        for (int b = 0; b < NBINS; ++b)
            Scum[b] = smS[0][b] + smS[1][b] + smS[2][b] + smS[3][b];
        for (int j = 0; j < NE; ++j)
            Ccum[j + 1] = smC[0][j] + smC[1][j] + smC[2][j] + smC[3][j];

        // de-cumulate; mimic reference f32 arithmetic for gd (cnt*ne can exceed 2^24)
        float ne = 0.0f;
        float cnt[NBINS], S[NBINS];
        for (int b = 0; b < NBINS; ++b) {
            cnt[b] = (float)(Ccum[b] - Ccum[b + 1]);
            S[b]   = (float)(Scum[b] - Scum[b + 1]);
            ne += (cnt[b] > 0.0f) ? 1.0f : 0.0f;
        }
        float tot = 0.0f;
        for (int b = 0; b < NBINS; ++b)
            tot += S[b] / fmaxf(cnt[b] * ne, 1e-4f);     // mean(w*bce) = sum_b S_b/gd_b
        out[0] = tot;
    }
}

extern "C" void kernel_launch(void* const* d_in, const int* in_sizes, int n_in,
                              void* d_out, int out_size, void* d_ws, size_t ws_size,
                              hipStream_t stream) {
    const float4* x = (const float4*)d_in[0];
    const float4* t = (const float4*)d_in[1];
    float* out = (float*)d_out;
    int n  = in_sizes[0];          // 4096*4096, divisible by 4
    int n4 = n >> 2;

    int nb = 2048;                 // 8 blocks/CU co-resident
    const size_t per = NBINS * sizeof(float) + NE * sizeof(u32);   // 76 B/block
    if (ws_size < (size_t)nb * per) {
        nb = (int)(ws_size / per);
        if (nb < 1) nb = 1;        // grid-stride keeps correctness at any nb
    }
    float* partS = (float*)d_ws;
    u32*   partC = (u32*)((char*)d_ws + (size_t)nb * NBINS * sizeof(float));

    ghm_pass1<<<nb, TPB, 0, stream>>>(x, t, partS, partC, n4);
    ghm_finalize<<<1, 256, 0, stream>>>(partS, partC, out, nb, (float)n);
}